// Round 1
// baseline (355.730 us; speedup 1.0000x reference)
//
#include <hip/hip_runtime.h>

#define BT 48
#define NN 2048
#define FF 64
#define EE 32768
#define ROWS (BT*NN)          // 98304
#define R_PER_BLK 96          // 1024 blocks

// ---------------- Kernel 1: fused projections ----------------
// out_col(row, col) = sum_k x[row][k] * W[k][col] + b[col]
// thread = (matrix m = tid>>6, col = tid&63). W column lives in 64 VGPRs.
// x-row loads are block-uniform -> scalar loads (s_load_dwordx4).
__global__ __launch_bounds__(256) void proj_kernel(
    const float* __restrict__ x,
    const float* __restrict__ Wk, const float* __restrict__ bk,
    const float* __restrict__ Wq, const float* __restrict__ bq,
    const float* __restrict__ Wv, const float* __restrict__ bv,
    const float* __restrict__ Ws, const float* __restrict__ bs,
    float* __restrict__ K, float* __restrict__ Q, float* __restrict__ V,
    float* __restrict__ out)
{
    const int tid = threadIdx.x;
    const int m   = tid >> 6;       // 0:K 1:Q 2:V 3:skip  (wave-uniform)
    const int col = tid & 63;
    const float* Wm = (m==0)?Wk:(m==1)?Wq:(m==2)?Wv:Ws;
    const float* bm = (m==0)?bk:(m==1)?bq:(m==2)?bv:bs;
    float* dptr     = (m==0)?K :(m==1)?Q :(m==2)?V :out;

    float w[64];
    #pragma unroll
    for (int k=0;k<64;k++) w[k] = Wm[k*64 + col];   // coalesced across lanes
    const float bias = bm[col];

    const int row0 = blockIdx.x * R_PER_BLK;
    for (int r=0; r<R_PER_BLK; r++){
        const int row = row0 + r;                    // uniform
        const float* xr = x + (size_t)row*FF;
        float acc = bias;
        #pragma unroll
        for (int k=0;k<64;k+=4){
            const float4 xv = *(const float4*)(xr + k);  // uniform addr -> s_load
            acc = fmaf(xv.x, w[k+0], acc);
            acc = fmaf(xv.y, w[k+1], acc);
            acc = fmaf(xv.z, w[k+2], acc);
            acc = fmaf(xv.w, w[k+3], acc);
        }
        dptr[(size_t)row*FF + col] = acc;
    }
}

// ---------------- Kernel 2: CSR build (single block) ----------------
// histogram(dst) -> exclusive scan -> place src into per-dst buckets.
// Detects int64 vs int32 edge_index at runtime (high words all zero -> int64).
__global__ __launch_bounds__(1024) void csr_kernel(
    const unsigned int* __restrict__ ew,  // 32-bit view of edge_index
    int* __restrict__ offs,               // [NN+1]
    int* __restrict__ elist)              // [EE] src per bucket
{
    __shared__ int deg[NN];
    __shared__ int cur[NN];
    __shared__ int wsum[16];
    __shared__ unsigned int flagOr;
    const int tid = threadIdx.x;
    if (tid==0) flagOr = 0u;
    for (int i=tid; i<NN; i+=1024) deg[i]=0;
    __syncthreads();
    unsigned int f = 0;
    for (int i=tid; i<8192; i+=1024) f |= ew[2*i+1]; // safe: word idx < 16384
    atomicOr(&flagOr, f);
    __syncthreads();
    const bool i64 = (flagOr == 0u);

    // histogram of dst
    for (int e=tid; e<EE; e+=1024){
        const int d = i64 ? (int)ew[2*(EE+e)] : (int)ew[EE+e];
        atomicAdd(&deg[d], 1);
    }
    __syncthreads();

    // exclusive scan over 2048 degrees (2 per thread, wave-scan + wave-offset scan)
    const int a = deg[2*tid], b = deg[2*tid+1];
    const int s2 = a + b;
    int inc = s2;
    const int lane = tid & 63, wid = tid >> 6;
    #pragma unroll
    for (int d=1; d<64; d<<=1){ int t = __shfl_up(inc, d, 64); if (lane>=d) inc += t; }
    if (lane==63) wsum[wid] = inc;
    __syncthreads();
    if (wid==0){
        int v = (lane<16) ? wsum[lane] : 0;
        int inc2 = v;
        #pragma unroll
        for (int d=1; d<16; d<<=1){ int t = __shfl_up(inc2, d, 64); if (lane>=d) inc2 += t; }
        if (lane<16) wsum[lane] = inc2 - v;  // exclusive wave offsets
    }
    __syncthreads();
    const int excl = wsum[wid] + (inc - s2);
    offs[2*tid]   = excl;
    offs[2*tid+1] = excl + a;
    cur[2*tid]    = excl;
    cur[2*tid+1]  = excl + a;
    if (tid==1023) offs[NN] = excl + a + b;  // = EE
    __syncthreads();

    // place edges
    for (int e=tid; e<EE; e+=1024){
        int d, s;
        if (i64){ d = (int)ew[2*(EE+e)]; s = (int)ew[2*e]; }
        else    { d = (int)ew[EE+e];     s = (int)ew[e];   }
        const int pos = atomicAdd(&cur[d], 1);
        elist[pos] = s;
    }
}

// ---------------- Kernel 3: gather + gate + aggregate ----------------
// one wave per (bt,node); lane = feature. out = skip + sum_e leaky(k_i+q_j)*v_j
__global__ __launch_bounds__(256) void agg_kernel(
    const float* __restrict__ K, const float* __restrict__ Q, const float* __restrict__ V,
    const int* __restrict__ offs, const int* __restrict__ elist,
    float* __restrict__ out)
{
    const int tid  = threadIdx.x;
    const int lane = tid & 63;
    const int w    = tid >> 6;
    const int gw   = blockIdx.x*4 + w;
    const int bt   = gw >> 11;          // node-fastest -> per-bt L2 locality
    const int node = gw & (NN-1);
    const size_t nb     = ((size_t)bt*NN + node)*FF;
    const size_t btBase = (size_t)bt*NN*FF;

    const float kf = K[nb + lane];
    float acc = out[nb + lane];          // skip + bias, written by proj_kernel
    const int s0 = offs[node], s1 = offs[node+1];
    for (int i=s0; i<s1; i++){
        const int s = elist[i];          // uniform per wave
        float g = kf + Q[btBase + (size_t)s*FF + lane];
        g = (g > 0.f) ? g : 0.01f*g;
        acc = fmaf(g, V[btBase + (size_t)s*FF + lane], acc);
    }
    out[nb + lane] = acc;
}

extern "C" void kernel_launch(void* const* d_in, const int* in_sizes, int n_in,
                              void* d_out, int out_size, void* d_ws, size_t ws_size,
                              hipStream_t stream)
{
    const float* x  = (const float*)d_in[0];
    const unsigned int* ew = (const unsigned int*)d_in[1];
    const float* Wk = (const float*)d_in[2];
    const float* bk = (const float*)d_in[3];
    const float* Wq = (const float*)d_in[4];
    const float* bq = (const float*)d_in[5];
    const float* Wv = (const float*)d_in[6];
    const float* bv = (const float*)d_in[7];
    const float* Ws = (const float*)d_in[8];
    const float* bs = (const float*)d_in[9];
    float* out = (float*)d_out;

    float* K = (float*)d_ws;
    const size_t n = (size_t)ROWS*FF;
    float* Q = K + n;
    float* V = Q + n;
    int* offs  = (int*)(V + n);
    int* elist = offs + (NN+1) + 3;   // keep 16B-ish alignment

    hipLaunchKernelGGL(proj_kernel, dim3(ROWS/R_PER_BLK), dim3(256), 0, stream,
                       x, Wk,bk, Wq,bq, Wv,bv, Ws,bs, K,Q,V, out);
    hipLaunchKernelGGL(csr_kernel, dim3(1), dim3(1024), 0, stream, ew, offs, elist);
    hipLaunchKernelGGL(agg_kernel, dim3(ROWS/4), dim3(256), 0, stream,
                       K, Q, V, offs, elist, out);
}

// Round 2
// 173.009 us; speedup vs baseline: 2.0561x; 2.0561x over previous
//
#include <hip/hip_runtime.h>

#define BT 48
#define NN 2048
#define FF 64
#define EE 32768
#define ROWS (BT*NN)          // 98304
#define PR_ROWS 32            // rows per proj block -> 3072 blocks

// ---------------- Kernel 1: fused projections ----------------
// Block = 256 threads: wave m = tid>>6 owns matrix m (0:K 1:Q 2:V 3:skip),
// col = tid&63. W column in 64 VGPRs. x tile (32 rows) staged in LDS with
// coalesced float4 loads; compute reads are LDS broadcasts. 4-row ILP.
__global__ __launch_bounds__(256) void proj_kernel(
    const float* __restrict__ x,
    const float* __restrict__ Wk, const float* __restrict__ bk,
    const float* __restrict__ Wq, const float* __restrict__ bq,
    const float* __restrict__ Wv, const float* __restrict__ bv,
    const float* __restrict__ Ws, const float* __restrict__ bs,
    float* __restrict__ K, float* __restrict__ Q, float* __restrict__ V,
    float* __restrict__ out)
{
    __shared__ float xs[PR_ROWS*FF];     // 8 KB
    const int tid = threadIdx.x;
    const int m   = tid >> 6;            // wave-uniform
    const int col = tid & 63;
    const float* Wm = (m==0)?Wk:(m==1)?Wq:(m==2)?Wv:Ws;
    const float* bm = (m==0)?bk:(m==1)?bq:(m==2)?bv:bs;
    float* dptr     = (m==0)?K :(m==1)?Q :(m==2)?V :out;

    float w[64];
    #pragma unroll
    for (int k=0;k<64;k++) w[k] = Wm[k*64 + col];   // coalesced across lanes
    const float bias = bm[col];

    const int row0 = blockIdx.x * PR_ROWS;
    // stage 32 rows (2048 floats = 512 float4) cooperatively
    const float4* xg = (const float4*)(x + (size_t)row0*FF);
    float4* xl = (float4*)xs;
    xl[tid]       = xg[tid];
    xl[tid + 256] = xg[tid + 256];
    __syncthreads();

    for (int r=0; r<PR_ROWS; r+=4){
        float a0=bias, a1=bias, a2=bias, a3=bias;
        const float4* p0 = (const float4*)(xs + (r+0)*FF);
        const float4* p1 = (const float4*)(xs + (r+1)*FF);
        const float4* p2 = (const float4*)(xs + (r+2)*FF);
        const float4* p3 = (const float4*)(xs + (r+3)*FF);
        #pragma unroll
        for (int k=0;k<16;k++){
            const float4 x0 = p0[k], x1 = p1[k], x2 = p2[k], x3 = p3[k];
            a0 = fmaf(x0.x, w[4*k+0], a0); a0 = fmaf(x0.y, w[4*k+1], a0);
            a0 = fmaf(x0.z, w[4*k+2], a0); a0 = fmaf(x0.w, w[4*k+3], a0);
            a1 = fmaf(x1.x, w[4*k+0], a1); a1 = fmaf(x1.y, w[4*k+1], a1);
            a1 = fmaf(x1.z, w[4*k+2], a1); a1 = fmaf(x1.w, w[4*k+3], a1);
            a2 = fmaf(x2.x, w[4*k+0], a2); a2 = fmaf(x2.y, w[4*k+1], a2);
            a2 = fmaf(x2.z, w[4*k+2], a2); a2 = fmaf(x2.w, w[4*k+3], a2);
            a3 = fmaf(x3.x, w[4*k+0], a3); a3 = fmaf(x3.y, w[4*k+1], a3);
            a3 = fmaf(x3.z, w[4*k+2], a3); a3 = fmaf(x3.w, w[4*k+3], a3);
        }
        const size_t ob = (size_t)(row0 + r)*FF + col;
        dptr[ob]        = a0;
        dptr[ob + FF]   = a1;
        dptr[ob + 2*FF] = a2;
        dptr[ob + 3*FF] = a3;
    }
}

// ---------------- Kernel 2: CSR build (single block) ----------------
__global__ __launch_bounds__(1024) void csr_kernel(
    const unsigned int* __restrict__ ew,  // 32-bit view of edge_index
    int* __restrict__ offs,               // [NN+1]
    int* __restrict__ elist)              // [EE] src per bucket
{
    __shared__ int deg[NN];
    __shared__ int cur[NN];
    __shared__ int wsum[16];
    __shared__ unsigned int flagOr;
    const int tid = threadIdx.x;
    if (tid==0) flagOr = 0u;
    for (int i=tid; i<NN; i+=1024) deg[i]=0;
    __syncthreads();
    unsigned int f = 0;
    for (int i=tid; i<8192; i+=1024) f |= ew[2*i+1];
    atomicOr(&flagOr, f);
    __syncthreads();
    const bool i64 = (flagOr == 0u);

    for (int e=tid; e<EE; e+=1024){
        const int d = i64 ? (int)ew[2*(EE+e)] : (int)ew[EE+e];
        atomicAdd(&deg[d], 1);
    }
    __syncthreads();

    const int a = deg[2*tid], b = deg[2*tid+1];
    const int s2 = a + b;
    int inc = s2;
    const int lane = tid & 63, wid = tid >> 6;
    #pragma unroll
    for (int d=1; d<64; d<<=1){ int t = __shfl_up(inc, d, 64); if (lane>=d) inc += t; }
    if (lane==63) wsum[wid] = inc;
    __syncthreads();
    if (wid==0){
        int v = (lane<16) ? wsum[lane] : 0;
        int inc2 = v;
        #pragma unroll
        for (int d=1; d<16; d<<=1){ int t = __shfl_up(inc2, d, 64); if (lane>=d) inc2 += t; }
        if (lane<16) wsum[lane] = inc2 - v;
    }
    __syncthreads();
    const int excl = wsum[wid] + (inc - s2);
    offs[2*tid]   = excl;
    offs[2*tid+1] = excl + a;
    cur[2*tid]    = excl;
    cur[2*tid+1]  = excl + a;
    if (tid==1023) offs[NN] = excl + a + b;
    __syncthreads();

    for (int e=tid; e<EE; e+=1024){
        int d, s;
        if (i64){ d = (int)ew[2*(EE+e)]; s = (int)ew[2*e]; }
        else    { d = (int)ew[EE+e];     s = (int)ew[e];   }
        const int pos = atomicAdd(&cur[d], 1);
        elist[pos] = s;
    }
}

// ---------------- Kernel 3: gather + gate + aggregate ----------------
// one wave per (bt,node); lane = feature; 4-edge unroll so 8 gathers are
// in flight before the dependent gate/FMA chain.
__global__ __launch_bounds__(256) void agg_kernel(
    const float* __restrict__ K, const float* __restrict__ Q, const float* __restrict__ V,
    const int* __restrict__ offs, const int* __restrict__ elist,
    float* __restrict__ out)
{
    const int tid  = threadIdx.x;
    const int lane = tid & 63;
    const int w    = tid >> 6;
    const int gw   = blockIdx.x*4 + w;
    const int bt   = gw >> 11;
    const int node = gw & (NN-1);
    const size_t nb     = ((size_t)bt*NN + node)*FF;
    const float* Qb = Q + (size_t)bt*NN*FF;
    const float* Vb = V + (size_t)bt*NN*FF;

    const float kf = K[nb + lane];
    float acc = out[nb + lane];
    const int s0 = offs[node], s1 = offs[node+1];
    int i = s0;
    for (; i+4 <= s1; i+=4){
        const int e0 = elist[i+0], e1 = elist[i+1];
        const int e2 = elist[i+2], e3 = elist[i+3];
        const float q0 = Qb[(size_t)e0*FF + lane];
        const float q1 = Qb[(size_t)e1*FF + lane];
        const float q2 = Qb[(size_t)e2*FF + lane];
        const float q3 = Qb[(size_t)e3*FF + lane];
        const float v0 = Vb[(size_t)e0*FF + lane];
        const float v1 = Vb[(size_t)e1*FF + lane];
        const float v2 = Vb[(size_t)e2*FF + lane];
        const float v3 = Vb[(size_t)e3*FF + lane];
        float g0 = kf + q0; g0 = (g0 > 0.f) ? g0 : 0.01f*g0;
        float g1 = kf + q1; g1 = (g1 > 0.f) ? g1 : 0.01f*g1;
        float g2 = kf + q2; g2 = (g2 > 0.f) ? g2 : 0.01f*g2;
        float g3 = kf + q3; g3 = (g3 > 0.f) ? g3 : 0.01f*g3;
        acc = fmaf(g0, v0, acc);
        acc = fmaf(g1, v1, acc);
        acc = fmaf(g2, v2, acc);
        acc = fmaf(g3, v3, acc);
    }
    for (; i < s1; i++){
        const int s = elist[i];
        float g = kf + Qb[(size_t)s*FF + lane];
        g = (g > 0.f) ? g : 0.01f*g;
        acc = fmaf(g, Vb[(size_t)s*FF + lane], acc);
    }
    out[nb + lane] = acc;
}

extern "C" void kernel_launch(void* const* d_in, const int* in_sizes, int n_in,
                              void* d_out, int out_size, void* d_ws, size_t ws_size,
                              hipStream_t stream)
{
    const float* x  = (const float*)d_in[0];
    const unsigned int* ew = (const unsigned int*)d_in[1];
    const float* Wk = (const float*)d_in[2];
    const float* bk = (const float*)d_in[3];
    const float* Wq = (const float*)d_in[4];
    const float* bq = (const float*)d_in[5];
    const float* Wv = (const float*)d_in[6];
    const float* bv = (const float*)d_in[7];
    const float* Ws = (const float*)d_in[8];
    const float* bs = (const float*)d_in[9];
    float* out = (float*)d_out;

    float* K = (float*)d_ws;
    const size_t n = (size_t)ROWS*FF;
    float* Q = K + n;
    float* V = Q + n;
    int* offs  = (int*)(V + n);
    int* elist = offs + (NN+1) + 3;

    hipLaunchKernelGGL(proj_kernel, dim3(ROWS/PR_ROWS), dim3(256), 0, stream,
                       x, Wk,bk, Wq,bq, Wv,bv, Ws,bs, K,Q,V, out);
    hipLaunchKernelGGL(csr_kernel, dim3(1), dim3(1024), 0, stream, ew, offs, elist);
    hipLaunchKernelGGL(agg_kernel, dim3(ROWS/4), dim3(256), 0, stream,
                       K, Q, V, offs, elist, out);
}

// Round 3
// 166.709 us; speedup vs baseline: 2.1338x; 1.0378x over previous
//
#include <hip/hip_runtime.h>

#define BT 48
#define NN 2048
#define FF 64
#define EE 32768
#define ROWS (BT*NN)          // 98304
#define PR_ROWS 32            // rows per proj block -> 3072 blocks
#define BTB 4                 // bt slices per agg wave

// ---------------- Kernel 1: fused projections ----------------
__global__ __launch_bounds__(256) void proj_kernel(
    const float* __restrict__ x,
    const float* __restrict__ Wk, const float* __restrict__ bk,
    const float* __restrict__ Wq, const float* __restrict__ bq,
    const float* __restrict__ Wv, const float* __restrict__ bv,
    const float* __restrict__ Ws, const float* __restrict__ bs,
    float* __restrict__ K, float* __restrict__ Q, float* __restrict__ V,
    float* __restrict__ out)
{
    __shared__ float xs[PR_ROWS*FF];     // 8 KB
    const int tid = threadIdx.x;
    const int m   = tid >> 6;            // wave-uniform: 0:K 1:Q 2:V 3:skip
    const int col = tid & 63;
    const float* Wm = (m==0)?Wk:(m==1)?Wq:(m==2)?Wv:Ws;
    const float* bm = (m==0)?bk:(m==1)?bq:(m==2)?bv:bs;
    float* dptr     = (m==0)?K :(m==1)?Q :(m==2)?V :out;

    float w[64];
    #pragma unroll
    for (int k=0;k<64;k++) w[k] = Wm[k*64 + col];
    const float bias = bm[col];

    const int row0 = blockIdx.x * PR_ROWS;
    const float4* xg = (const float4*)(x + (size_t)row0*FF);
    float4* xl = (float4*)xs;
    xl[tid]       = xg[tid];
    xl[tid + 256] = xg[tid + 256];
    __syncthreads();

    for (int r=0; r<PR_ROWS; r+=4){
        float a0=bias, a1=bias, a2=bias, a3=bias;
        const float4* p0 = (const float4*)(xs + (r+0)*FF);
        const float4* p1 = (const float4*)(xs + (r+1)*FF);
        const float4* p2 = (const float4*)(xs + (r+2)*FF);
        const float4* p3 = (const float4*)(xs + (r+3)*FF);
        #pragma unroll
        for (int k=0;k<16;k++){
            const float4 x0 = p0[k], x1 = p1[k], x2 = p2[k], x3 = p3[k];
            a0 = fmaf(x0.x, w[4*k+0], a0); a0 = fmaf(x0.y, w[4*k+1], a0);
            a0 = fmaf(x0.z, w[4*k+2], a0); a0 = fmaf(x0.w, w[4*k+3], a0);
            a1 = fmaf(x1.x, w[4*k+0], a1); a1 = fmaf(x1.y, w[4*k+1], a1);
            a1 = fmaf(x1.z, w[4*k+2], a1); a1 = fmaf(x1.w, w[4*k+3], a1);
            a2 = fmaf(x2.x, w[4*k+0], a2); a2 = fmaf(x2.y, w[4*k+1], a2);
            a2 = fmaf(x2.z, w[4*k+2], a2); a2 = fmaf(x2.w, w[4*k+3], a2);
            a3 = fmaf(x3.x, w[4*k+0], a3); a3 = fmaf(x3.y, w[4*k+1], a3);
            a3 = fmaf(x3.z, w[4*k+2], a3); a3 = fmaf(x3.w, w[4*k+3], a3);
        }
        const size_t ob = (size_t)(row0 + r)*FF + col;
        dptr[ob]        = a0;
        dptr[ob + FF]   = a1;
        dptr[ob + 2*FF] = a2;
        dptr[ob + 3*FF] = a3;
    }
}

// ---------------- CSR build: 4 small parallel kernels ----------------
// k0: detect int64-vs-int32 + zero deg
__global__ __launch_bounds__(256) void csr_init_kernel(
    const unsigned int* __restrict__ ew, int* __restrict__ flag, int* __restrict__ deg)
{
    const int tid = threadIdx.x;
    if (tid == 0) *flag = 0;
    for (int i=tid; i<NN; i+=256) deg[i] = 0;
    __syncthreads();
    // OR the high words of the first 8192 (int64) entries; if dtype is int32
    // these words are actual node ids (some nonzero with prob ~1).
    unsigned int f = 0;
    for (int i=tid; i<8192; i+=256) f |= ew[2*i+1];
    if (f) atomicOr((unsigned int*)flag, f);
}

// k1: histogram of dst via global atomics
__global__ __launch_bounds__(256) void csr_hist_kernel(
    const unsigned int* __restrict__ ew, const int* __restrict__ flag, int* __restrict__ deg)
{
    const bool i64 = (*flag == 0);
    const int gtid = blockIdx.x*256 + threadIdx.x;   // 16384 threads
    for (int e=gtid; e<EE; e+=16384){
        const int d = i64 ? (int)ew[2*(EE+e)] : (int)ew[EE+e];
        atomicAdd(&deg[d], 1);
    }
}

// k2: exclusive scan over 2048 degrees (single block)
__global__ __launch_bounds__(1024) void csr_scan_kernel(
    const int* __restrict__ deg, int* __restrict__ offs, int* __restrict__ cur)
{
    __shared__ int wsum[16];
    const int tid = threadIdx.x;
    const int a = deg[2*tid], b = deg[2*tid+1];
    const int s2 = a + b;
    int inc = s2;
    const int lane = tid & 63, wid = tid >> 6;
    #pragma unroll
    for (int d=1; d<64; d<<=1){ int t = __shfl_up(inc, d, 64); if (lane>=d) inc += t; }
    if (lane==63) wsum[wid] = inc;
    __syncthreads();
    if (wid==0){
        int v = (lane<16) ? wsum[lane] : 0;
        int inc2 = v;
        #pragma unroll
        for (int d=1; d<16; d<<=1){ int t = __shfl_up(inc2, d, 64); if (lane>=d) inc2 += t; }
        if (lane<16) wsum[lane] = inc2 - v;
    }
    __syncthreads();
    const int excl = wsum[wid] + (inc - s2);
    offs[2*tid]   = excl;
    offs[2*tid+1] = excl + a;
    cur[2*tid]    = excl;
    cur[2*tid+1]  = excl + a;
    if (tid==1023) offs[NN] = excl + a + b;
}

// k3: place src into per-dst buckets via global atomic cursors
__global__ __launch_bounds__(256) void csr_place_kernel(
    const unsigned int* __restrict__ ew, const int* __restrict__ flag,
    int* __restrict__ cur, int* __restrict__ elist)
{
    const bool i64 = (*flag == 0);
    const int gtid = blockIdx.x*256 + threadIdx.x;
    for (int e=gtid; e<EE; e+=16384){
        int d, s;
        if (i64){ d = (int)ew[2*(EE+e)]; s = (int)ew[2*e]; }
        else    { d = (int)ew[EE+e];     s = (int)ew[e];   }
        const int pos = atomicAdd(&cur[d], 1);
        elist[pos] = s;
    }
}

// ---------------- Kernel 3: gather + gate + aggregate ----------------
// one wave per (btg,node): 4 bt slices per wave, lane = feature.
// 2-edge unroll x 4 bt x {Q,V} = 16 independent gathers in flight per
// elist load; elist/offs/addr work amortized 4x.
__global__ __launch_bounds__(256) void agg_kernel(
    const float* __restrict__ K, const float* __restrict__ Q, const float* __restrict__ V,
    const int* __restrict__ offs, const int* __restrict__ elist,
    float* __restrict__ out)
{
    const int tid  = threadIdx.x;
    const int lane = tid & 63;
    const int w    = tid >> 6;
    const int gw   = blockIdx.x*4 + w;
    const int btg  = gw >> 11;          // node-fastest within btg
    const int node = gw & (NN-1);
    const int bt0  = btg * BTB;
    const size_t S  = (size_t)NN*FF;
    const size_t nb = (size_t)bt0*S + (size_t)node*FF + lane;

    const float kf0 = K[nb], kf1 = K[nb+S], kf2 = K[nb+2*S], kf3 = K[nb+3*S];
    float a0 = out[nb], a1 = out[nb+S], a2 = out[nb+2*S], a3 = out[nb+3*S];

    const float* Q0 = Q + (size_t)bt0*S + lane;
    const float* Q1 = Q0 + S; const float* Q2 = Q0 + 2*S; const float* Q3 = Q0 + 3*S;
    const float* V0 = V + (size_t)bt0*S + lane;
    const float* V1 = V0 + S; const float* V2 = V0 + 2*S; const float* V3 = V0 + 3*S;

    const int s0 = offs[node], s1 = offs[node+1];
    int i = s0;
    for (; i+2 <= s1; i+=2){
        const size_t o0 = (size_t)elist[i]   * FF;
        const size_t o1 = (size_t)elist[i+1] * FF;
        const float q00=Q0[o0], q10=Q1[o0], q20=Q2[o0], q30=Q3[o0];
        const float q01=Q0[o1], q11=Q1[o1], q21=Q2[o1], q31=Q3[o1];
        const float v00=V0[o0], v10=V1[o0], v20=V2[o0], v30=V3[o0];
        const float v01=V0[o1], v11=V1[o1], v21=V2[o1], v31=V3[o1];
        float g;
        g = kf0+q00; g = (g>0.f)?g:0.01f*g; a0 = fmaf(g, v00, a0);
        g = kf1+q10; g = (g>0.f)?g:0.01f*g; a1 = fmaf(g, v10, a1);
        g = kf2+q20; g = (g>0.f)?g:0.01f*g; a2 = fmaf(g, v20, a2);
        g = kf3+q30; g = (g>0.f)?g:0.01f*g; a3 = fmaf(g, v30, a3);
        g = kf0+q01; g = (g>0.f)?g:0.01f*g; a0 = fmaf(g, v01, a0);
        g = kf1+q11; g = (g>0.f)?g:0.01f*g; a1 = fmaf(g, v11, a1);
        g = kf2+q21; g = (g>0.f)?g:0.01f*g; a2 = fmaf(g, v21, a2);
        g = kf3+q31; g = (g>0.f)?g:0.01f*g; a3 = fmaf(g, v31, a3);
    }
    for (; i < s1; i++){
        const size_t o = (size_t)elist[i] * FF;
        const float q0=Q0[o], q1=Q1[o], q2=Q2[o], q3=Q3[o];
        const float v0=V0[o], v1=V1[o], v2=V2[o], v3=V3[o];
        float g;
        g = kf0+q0; g = (g>0.f)?g:0.01f*g; a0 = fmaf(g, v0, a0);
        g = kf1+q1; g = (g>0.f)?g:0.01f*g; a1 = fmaf(g, v1, a1);
        g = kf2+q2; g = (g>0.f)?g:0.01f*g; a2 = fmaf(g, v2, a2);
        g = kf3+q3; g = (g>0.f)?g:0.01f*g; a3 = fmaf(g, v3, a3);
    }
    out[nb]     = a0;
    out[nb+S]   = a1;
    out[nb+2*S] = a2;
    out[nb+3*S] = a3;
}

extern "C" void kernel_launch(void* const* d_in, const int* in_sizes, int n_in,
                              void* d_out, int out_size, void* d_ws, size_t ws_size,
                              hipStream_t stream)
{
    const float* x  = (const float*)d_in[0];
    const unsigned int* ew = (const unsigned int*)d_in[1];
    const float* Wk = (const float*)d_in[2];
    const float* bk = (const float*)d_in[3];
    const float* Wq = (const float*)d_in[4];
    const float* bq = (const float*)d_in[5];
    const float* Wv = (const float*)d_in[6];
    const float* bv = (const float*)d_in[7];
    const float* Ws = (const float*)d_in[8];
    const float* bs = (const float*)d_in[9];
    float* out = (float*)d_out;

    float* K = (float*)d_ws;
    const size_t n = (size_t)ROWS*FF;
    float* Q = K + n;
    float* V = Q + n;
    int* meta  = (int*)(V + n);
    int* flag  = meta;
    int* deg   = meta + 16;
    int* offs  = deg + NN;
    int* cur   = offs + NN + 16;
    int* elist = cur + NN;

    hipLaunchKernelGGL(proj_kernel, dim3(ROWS/PR_ROWS), dim3(256), 0, stream,
                       x, Wk,bk, Wq,bq, Wv,bv, Ws,bs, K,Q,V, out);
    hipLaunchKernelGGL(csr_init_kernel,  dim3(1),  dim3(256),  0, stream, ew, flag, deg);
    hipLaunchKernelGGL(csr_hist_kernel,  dim3(64), dim3(256),  0, stream, ew, flag, deg);
    hipLaunchKernelGGL(csr_scan_kernel,  dim3(1),  dim3(1024), 0, stream, deg, offs, cur);
    hipLaunchKernelGGL(csr_place_kernel, dim3(64), dim3(256),  0, stream, ew, flag, cur, elist);
    hipLaunchKernelGGL(agg_kernel, dim3(ROWS/(4*BTB)), dim3(256), 0, stream,
                       K, Q, V, offs, elist, out);
}

// Round 4
// 127.851 us; speedup vs baseline: 2.7824x; 1.3039x over previous
//
#include <hip/hip_runtime.h>

#define BT 48
#define NN 2048
#define FF 64
#define EE 32768
#define ROWS (BT*NN)          // 98304
#define PR_ROWS 32            // rows per proj block -> 3072 blocks

// ---------------- Kernel 1: fused projections ----------------
// Block = 128 threads (2 waves). Wave 0: mats K,Q; wave 1: mats V,skip.
// Each thread owns one column of TWO weight matrices (128 VGPRs), so each
// x LDS-broadcast read feeds 2x the FMAs (halves LDS issue pressure).
__global__ __launch_bounds__(128, 2) void proj_kernel(
    const float* __restrict__ x,
    const float* __restrict__ Wk, const float* __restrict__ bk,
    const float* __restrict__ Wq, const float* __restrict__ bq,
    const float* __restrict__ Wv, const float* __restrict__ bv,
    const float* __restrict__ Ws, const float* __restrict__ bs,
    float* __restrict__ K, float* __restrict__ Q, float* __restrict__ V,
    float* __restrict__ out)
{
    __shared__ float xs[PR_ROWS*FF];     // 8 KB
    const int tid = threadIdx.x;         // 0..127
    const int w   = tid >> 6;            // wave id: 0 or 1
    const int col = tid & 63;
    const float* WA = (w==0) ? Wk : Wv;
    const float* WB = (w==0) ? Wq : Ws;
    float* dA       = (w==0) ? K  : V;
    float* dB       = (w==0) ? Q  : out;
    const float bA  = (w==0) ? bk[col] : bv[col];
    const float bB  = (w==0) ? bq[col] : bs[col];

    float wA[64], wB[64];
    #pragma unroll
    for (int k=0;k<64;k++){ wA[k] = WA[k*64 + col]; wB[k] = WB[k*64 + col]; }

    const int row0 = blockIdx.x * PR_ROWS;
    const float4* xg = (const float4*)(x + (size_t)row0*FF);
    float4* xl = (float4*)xs;
    #pragma unroll
    for (int i=0;i<4;i++) xl[tid + 128*i] = xg[tid + 128*i];
    __syncthreads();

    for (int r=0; r<PR_ROWS; r+=4){
        float a0=bA,a1=bA,a2=bA,a3=bA;
        float b0=bB,b1=bB,b2=bB,b3=bB;
        const float4* p0 = (const float4*)(xs + (r+0)*FF);
        const float4* p1 = (const float4*)(xs + (r+1)*FF);
        const float4* p2 = (const float4*)(xs + (r+2)*FF);
        const float4* p3 = (const float4*)(xs + (r+3)*FF);
        #pragma unroll
        for (int k=0;k<16;k++){
            const float4 x0 = p0[k], x1 = p1[k], x2 = p2[k], x3 = p3[k];
            a0 = fmaf(x0.x, wA[4*k+0], a0); a0 = fmaf(x0.y, wA[4*k+1], a0);
            a0 = fmaf(x0.z, wA[4*k+2], a0); a0 = fmaf(x0.w, wA[4*k+3], a0);
            b0 = fmaf(x0.x, wB[4*k+0], b0); b0 = fmaf(x0.y, wB[4*k+1], b0);
            b0 = fmaf(x0.z, wB[4*k+2], b0); b0 = fmaf(x0.w, wB[4*k+3], b0);
            a1 = fmaf(x1.x, wA[4*k+0], a1); a1 = fmaf(x1.y, wA[4*k+1], a1);
            a1 = fmaf(x1.z, wA[4*k+2], a1); a1 = fmaf(x1.w, wA[4*k+3], a1);
            b1 = fmaf(x1.x, wB[4*k+0], b1); b1 = fmaf(x1.y, wB[4*k+1], b1);
            b1 = fmaf(x1.z, wB[4*k+2], b1); b1 = fmaf(x1.w, wB[4*k+3], b1);
            a2 = fmaf(x2.x, wA[4*k+0], a2); a2 = fmaf(x2.y, wA[4*k+1], a2);
            a2 = fmaf(x2.z, wA[4*k+2], a2); a2 = fmaf(x2.w, wA[4*k+3], a2);
            b2 = fmaf(x2.x, wB[4*k+0], b2); b2 = fmaf(x2.y, wB[4*k+1], b2);
            b2 = fmaf(x2.z, wB[4*k+2], b2); b2 = fmaf(x2.w, wB[4*k+3], b2);
            a3 = fmaf(x3.x, wA[4*k+0], a3); a3 = fmaf(x3.y, wA[4*k+1], a3);
            a3 = fmaf(x3.z, wA[4*k+2], a3); a3 = fmaf(x3.w, wA[4*k+3], a3);
            b3 = fmaf(x3.x, wB[4*k+0], b3); b3 = fmaf(x3.y, wB[4*k+1], b3);
            b3 = fmaf(x3.z, wB[4*k+2], b3); b3 = fmaf(x3.w, wB[4*k+3], b3);
        }
        const size_t ob = (size_t)(row0 + r)*FF + col;
        dA[ob]        = a0;  dB[ob]        = b0;
        dA[ob + FF]   = a1;  dB[ob + FF]   = b1;
        dA[ob + 2*FF] = a2;  dB[ob + 2*FF] = b2;
        dA[ob + 3*FF] = a3;  dB[ob + 3*FF] = b3;
    }
}

// ---------------- CSR build: 4 small parallel kernels ----------------
__global__ __launch_bounds__(256) void csr_init_kernel(
    const unsigned int* __restrict__ ew, int* __restrict__ flag, int* __restrict__ deg)
{
    const int tid = threadIdx.x;
    if (tid == 0) *flag = 0;
    for (int i=tid; i<NN; i+=256) deg[i] = 0;
    __syncthreads();
    unsigned int f = 0;
    for (int i=tid; i<8192; i+=256) f |= ew[2*i+1];
    if (f) atomicOr((unsigned int*)flag, f);
}

__global__ __launch_bounds__(256) void csr_hist_kernel(
    const unsigned int* __restrict__ ew, const int* __restrict__ flag, int* __restrict__ deg)
{
    const bool i64 = (*flag == 0);
    const int gtid = blockIdx.x*256 + threadIdx.x;   // 16384 threads
    for (int e=gtid; e<EE; e+=16384){
        const int d = i64 ? (int)ew[2*(EE+e)] : (int)ew[EE+e];
        atomicAdd(&deg[d], 1);
    }
}

__global__ __launch_bounds__(1024) void csr_scan_kernel(
    const int* __restrict__ deg, int* __restrict__ offs, int* __restrict__ cur)
{
    __shared__ int wsum[16];
    const int tid = threadIdx.x;
    const int a = deg[2*tid], b = deg[2*tid+1];
    const int s2 = a + b;
    int inc = s2;
    const int lane = tid & 63, wid = tid >> 6;
    #pragma unroll
    for (int d=1; d<64; d<<=1){ int t = __shfl_up(inc, d, 64); if (lane>=d) inc += t; }
    if (lane==63) wsum[wid] = inc;
    __syncthreads();
    if (wid==0){
        int v = (lane<16) ? wsum[lane] : 0;
        int inc2 = v;
        #pragma unroll
        for (int d=1; d<16; d<<=1){ int t = __shfl_up(inc2, d, 64); if (lane>=d) inc2 += t; }
        if (lane<16) wsum[lane] = inc2 - v;
    }
    __syncthreads();
    const int excl = wsum[wid] + (inc - s2);
    offs[2*tid]   = excl;
    offs[2*tid+1] = excl + a;
    cur[2*tid]    = excl;
    cur[2*tid+1]  = excl + a;
    if (tid==1023) offs[NN] = excl + a + b;
}

__global__ __launch_bounds__(256) void csr_place_kernel(
    const unsigned int* __restrict__ ew, const int* __restrict__ flag,
    int* __restrict__ cur, int* __restrict__ elist)
{
    const bool i64 = (*flag == 0);
    const int gtid = blockIdx.x*256 + threadIdx.x;
    for (int e=gtid; e<EE; e+=16384){
        int d, s;
        if (i64){ d = (int)ew[2*(EE+e)]; s = (int)ew[2*e]; }
        else    { d = (int)ew[EE+e];     s = (int)ew[e];   }
        const int pos = atomicAdd(&cur[d], 1);
        elist[pos] = s;
    }
}

// ---------------- Kernel 3: gather + gate + aggregate ----------------
// one wave per (bt,node), lane = feature. XCD-pinned: dispatch maps block b
// to XCD b%8, so we assign bt = xcd*6 + (b>>3)/512 -> all 2048 node-waves of
// a bt run on ONE XCD; its 4MB L2 holds that bt's 1MB Q+V slice.
__global__ __launch_bounds__(256) void agg_kernel(
    const float* __restrict__ K, const float* __restrict__ Q, const float* __restrict__ V,
    const int* __restrict__ offs, const int* __restrict__ elist,
    float* __restrict__ out)
{
    const int tid  = threadIdx.x;
    const int lane = tid & 63;
    const int w    = tid >> 6;
    const int b    = blockIdx.x;          // 24576 blocks
    const int xcd  = b & 7;
    const int li   = b >> 3;              // 0..3071
    const int bt   = xcd*6 + (li >> 9);   // 6 bts per XCD
    const int node = ((li & 511) << 2) | w;
    const size_t S  = (size_t)NN*FF;
    const size_t nb = (size_t)bt*S + (size_t)node*FF + lane;

    const float* Qb = Q + (size_t)bt*S + lane;
    const float* Vb = V + (size_t)bt*S + lane;

    const float kf = K[nb];
    float acc = out[nb];                  // skip + bias from proj
    const int s0 = offs[node], s1 = offs[node+1];
    int i = s0;
    for (; i+8 <= s1; i+=8){
        size_t o[8];
        #pragma unroll
        for (int j=0;j<8;j++) o[j] = (size_t)elist[i+j] * FF;
        float q[8], v[8];
        #pragma unroll
        for (int j=0;j<8;j++) q[j] = Qb[o[j]];
        #pragma unroll
        for (int j=0;j<8;j++) v[j] = Vb[o[j]];
        #pragma unroll
        for (int j=0;j<8;j++){
            float g = kf + q[j];
            g = (g > 0.f) ? g : 0.01f*g;
            acc = fmaf(g, v[j], acc);
        }
    }
    for (; i < s1; i++){
        const size_t o = (size_t)elist[i] * FF;
        float g = kf + Qb[o];
        g = (g > 0.f) ? g : 0.01f*g;
        acc = fmaf(g, Vb[o], acc);
    }
    out[nb] = acc;
}

extern "C" void kernel_launch(void* const* d_in, const int* in_sizes, int n_in,
                              void* d_out, int out_size, void* d_ws, size_t ws_size,
                              hipStream_t stream)
{
    const float* x  = (const float*)d_in[0];
    const unsigned int* ew = (const unsigned int*)d_in[1];
    const float* Wk = (const float*)d_in[2];
    const float* bk = (const float*)d_in[3];
    const float* Wq = (const float*)d_in[4];
    const float* bq = (const float*)d_in[5];
    const float* Wv = (const float*)d_in[6];
    const float* bv = (const float*)d_in[7];
    const float* Ws = (const float*)d_in[8];
    const float* bs = (const float*)d_in[9];
    float* out = (float*)d_out;

    float* K = (float*)d_ws;
    const size_t n = (size_t)ROWS*FF;
    float* Q = K + n;
    float* V = Q + n;
    int* meta  = (int*)(V + n);
    int* flag  = meta;
    int* deg   = meta + 16;
    int* offs  = deg + NN;
    int* cur   = offs + NN + 16;
    int* elist = cur + NN;

    hipLaunchKernelGGL(proj_kernel, dim3(ROWS/PR_ROWS), dim3(128), 0, stream,
                       x, Wk,bk, Wq,bq, Wv,bv, Ws,bs, K,Q,V, out);
    hipLaunchKernelGGL(csr_init_kernel,  dim3(1),  dim3(256),  0, stream, ew, flag, deg);
    hipLaunchKernelGGL(csr_hist_kernel,  dim3(64), dim3(256),  0, stream, ew, flag, deg);
    hipLaunchKernelGGL(csr_scan_kernel,  dim3(1),  dim3(1024), 0, stream, deg, offs, cur);
    hipLaunchKernelGGL(csr_place_kernel, dim3(64), dim3(256),  0, stream, ew, flag, cur, elist);
    hipLaunchKernelGGL(agg_kernel, dim3(ROWS/4), dim3(256), 0, stream,
                       K, Q, V, offs, elist, out);
}

// Round 5
// 127.141 us; speedup vs baseline: 2.7979x; 1.0056x over previous
//
#include <hip/hip_runtime.h>

#define BT 48
#define NN 2048
#define FF 64
#define EE 32768
#define ROWS (BT*NN)          // 98304
#define PR_ROWS 32            // rows per proj block -> 3072 blocks

// ---------------- Kernel 1: fused projections ----------------
// Block = 128 threads (2 waves). Wave 0: mats K,Q; wave 1: mats V,skip.
// Each thread owns one column of TWO weight matrices; at the ~21us fp32
// FMA-issue floor (3.2 GFLOP / 157 TF).
__global__ __launch_bounds__(128, 2) void proj_kernel(
    const float* __restrict__ x,
    const float* __restrict__ Wk, const float* __restrict__ bk,
    const float* __restrict__ Wq, const float* __restrict__ bq,
    const float* __restrict__ Wv, const float* __restrict__ bv,
    const float* __restrict__ Ws, const float* __restrict__ bs,
    float* __restrict__ K, float* __restrict__ Q, float* __restrict__ V,
    float* __restrict__ out)
{
    __shared__ float xs[PR_ROWS*FF];     // 8 KB
    const int tid = threadIdx.x;         // 0..127
    const int w   = tid >> 6;            // wave id: 0 or 1
    const int col = tid & 63;
    const float* WA = (w==0) ? Wk : Wv;
    const float* WB = (w==0) ? Wq : Ws;
    float* dA       = (w==0) ? K  : V;
    float* dB       = (w==0) ? Q  : out;
    const float bA  = (w==0) ? bk[col] : bv[col];
    const float bB  = (w==0) ? bq[col] : bs[col];

    float wA[64], wB[64];
    #pragma unroll
    for (int k=0;k<64;k++){ wA[k] = WA[k*64 + col]; wB[k] = WB[k*64 + col]; }

    const int row0 = blockIdx.x * PR_ROWS;
    const float4* xg = (const float4*)(x + (size_t)row0*FF);
    float4* xl = (float4*)xs;
    #pragma unroll
    for (int i=0;i<4;i++) xl[tid + 128*i] = xg[tid + 128*i];
    __syncthreads();

    for (int r=0; r<PR_ROWS; r+=4){
        float a0=bA,a1=bA,a2=bA,a3=bA;
        float b0=bB,b1=bB,b2=bB,b3=bB;
        const float4* p0 = (const float4*)(xs + (r+0)*FF);
        const float4* p1 = (const float4*)(xs + (r+1)*FF);
        const float4* p2 = (const float4*)(xs + (r+2)*FF);
        const float4* p3 = (const float4*)(xs + (r+3)*FF);
        #pragma unroll
        for (int k=0;k<16;k++){
            const float4 x0 = p0[k], x1 = p1[k], x2 = p2[k], x3 = p3[k];
            a0 = fmaf(x0.x, wA[4*k+0], a0); a0 = fmaf(x0.y, wA[4*k+1], a0);
            a0 = fmaf(x0.z, wA[4*k+2], a0); a0 = fmaf(x0.w, wA[4*k+3], a0);
            b0 = fmaf(x0.x, wB[4*k+0], b0); b0 = fmaf(x0.y, wB[4*k+1], b0);
            b0 = fmaf(x0.z, wB[4*k+2], b0); b0 = fmaf(x0.w, wB[4*k+3], b0);
            a1 = fmaf(x1.x, wA[4*k+0], a1); a1 = fmaf(x1.y, wA[4*k+1], a1);
            a1 = fmaf(x1.z, wA[4*k+2], a1); a1 = fmaf(x1.w, wA[4*k+3], a1);
            b1 = fmaf(x1.x, wB[4*k+0], b1); b1 = fmaf(x1.y, wB[4*k+1], b1);
            b1 = fmaf(x1.z, wB[4*k+2], b1); b1 = fmaf(x1.w, wB[4*k+3], b1);
            a2 = fmaf(x2.x, wA[4*k+0], a2); a2 = fmaf(x2.y, wA[4*k+1], a2);
            a2 = fmaf(x2.z, wA[4*k+2], a2); a2 = fmaf(x2.w, wA[4*k+3], a2);
            b2 = fmaf(x2.x, wB[4*k+0], b2); b2 = fmaf(x2.y, wB[4*k+1], b2);
            b2 = fmaf(x2.z, wB[4*k+2], b2); b2 = fmaf(x2.w, wB[4*k+3], b2);
            a3 = fmaf(x3.x, wA[4*k+0], a3); a3 = fmaf(x3.y, wA[4*k+1], a3);
            a3 = fmaf(x3.z, wA[4*k+2], a3); a3 = fmaf(x3.w, wA[4*k+3], a3);
            b3 = fmaf(x3.x, wB[4*k+0], b3); b3 = fmaf(x3.y, wB[4*k+1], b3);
            b3 = fmaf(x3.z, wB[4*k+2], b3); b3 = fmaf(x3.w, wB[4*k+3], b3);
        }
        const size_t ob = (size_t)(row0 + r)*FF + col;
        dA[ob]        = a0;  dB[ob]        = b0;
        dA[ob + FF]   = a1;  dB[ob + FF]   = b1;
        dA[ob + 2*FF] = a2;  dB[ob + 2*FF] = b2;
        dA[ob + 3*FF] = a3;  dB[ob + 3*FF] = b3;
    }
}

// ---------------- CSR build: 4 small parallel kernels ----------------
__global__ __launch_bounds__(256) void csr_init_kernel(
    const unsigned int* __restrict__ ew, int* __restrict__ flag, int* __restrict__ deg,
    int* __restrict__ elist)
{
    const int tid = threadIdx.x;
    if (tid == 0) *flag = 0;
    if (tid < 8) elist[EE + tid] = 0;     // pad: agg's 8-edge loop may read past s1
    for (int i=tid; i<NN; i+=256) deg[i] = 0;
    __syncthreads();
    unsigned int f = 0;
    for (int i=tid; i<8192; i+=256) f |= ew[2*i+1];
    if (f) atomicOr((unsigned int*)flag, f);
}

__global__ __launch_bounds__(256) void csr_hist_kernel(
    const unsigned int* __restrict__ ew, const int* __restrict__ flag, int* __restrict__ deg)
{
    const bool i64 = (*flag == 0);
    const int gtid = blockIdx.x*256 + threadIdx.x;   // 16384 threads
    for (int e=gtid; e<EE; e+=16384){
        const int d = i64 ? (int)ew[2*(EE+e)] : (int)ew[EE+e];
        atomicAdd(&deg[d], 1);
    }
}

__global__ __launch_bounds__(1024) void csr_scan_kernel(
    const int* __restrict__ deg, int* __restrict__ offs, int* __restrict__ cur)
{
    __shared__ int wsum[16];
    const int tid = threadIdx.x;
    const int a = deg[2*tid], b = deg[2*tid+1];
    const int s2 = a + b;
    int inc = s2;
    const int lane = tid & 63, wid = tid >> 6;
    #pragma unroll
    for (int d=1; d<64; d<<=1){ int t = __shfl_up(inc, d, 64); if (lane>=d) inc += t; }
    if (lane==63) wsum[wid] = inc;
    __syncthreads();
    if (wid==0){
        int v = (lane<16) ? wsum[lane] : 0;
        int inc2 = v;
        #pragma unroll
        for (int d=1; d<16; d<<=1){ int t = __shfl_up(inc2, d, 64); if (lane>=d) inc2 += t; }
        if (lane<16) wsum[lane] = inc2 - v;
    }
    __syncthreads();
    const int excl = wsum[wid] + (inc - s2);
    offs[2*tid]   = excl;
    offs[2*tid+1] = excl + a;
    cur[2*tid]    = excl;
    cur[2*tid+1]  = excl + a;
    if (tid==1023) offs[NN] = excl + a + b;
}

__global__ __launch_bounds__(256) void csr_place_kernel(
    const unsigned int* __restrict__ ew, const int* __restrict__ flag,
    int* __restrict__ cur, int* __restrict__ elist)
{
    const bool i64 = (*flag == 0);
    const int gtid = blockIdx.x*256 + threadIdx.x;
    for (int e=gtid; e<EE; e+=16384){
        int d, s;
        if (i64){ d = (int)ew[2*(EE+e)]; s = (int)ew[2*e]; }
        else    { d = (int)ew[EE+e];     s = (int)ew[e];   }
        const int pos = atomicAdd(&cur[d], 1);
        elist[pos] = s;
    }
}

// ---------------- Kernel 3: gather + gate + aggregate ----------------
// wave = (bt,node); lane = (sub = lane>>4 edge slot, fq = lane&15 feature
// quad). 8 edges per iter: 2 elist loads + 4 dwordx4 gathers + 32 gate
// VALU ~= 5 instr/edge (vs ~13 scalar). Edge->slot order is arbitrary
// (sum commutes); shfl_xor(16/32) merges the 4 groups at the end.
// XCD-pinned: block b -> XCD b%8 -> bt = xcd*6 + ..., so each bt's 1MB
// Q+V slice stays in one XCD's 4MB L2.
__global__ __launch_bounds__(256) void agg_kernel(
    const float* __restrict__ K, const float* __restrict__ Q, const float* __restrict__ V,
    const int* __restrict__ offs, const int* __restrict__ elist,
    float* __restrict__ out)
{
    const int tid  = threadIdx.x;
    const int lane = tid & 63;
    const int w    = tid >> 6;
    const int b    = blockIdx.x;          // 24576 blocks
    const int xcd  = b & 7;
    const int li   = b >> 3;              // 0..3071
    const int bt   = xcd*6 + (li >> 9);   // 6 bts per XCD
    const int node = ((li & 511) << 2) | w;
    const int sub  = lane >> 4;           // edge slot pair 0..3
    const int fq   = lane & 15;           // feature quad 0..15
    const size_t S  = (size_t)NN*FF;
    const size_t rowb = (size_t)bt*S + (size_t)node*FF;

    const float4 kf = *(const float4*)(K + rowb + fq*4);
    const float* Qb = Q + (size_t)bt*S;
    const float* Vb = V + (size_t)bt*S;

    float4 acc = {0.f,0.f,0.f,0.f};
    const int s0 = offs[node], s1 = offs[node+1];

    for (int i = s0; i < s1; i += 8){
        const int rem = s1 - i;           // wave-uniform
        const int i0 = i + 2*sub, i1 = i + 2*sub + 1;   // may read pad (zeros)
        const int e0 = elist[i0];
        const int e1 = elist[i1];
        const unsigned o0 = ((unsigned)e0 << 6) + (fq << 2);
        const unsigned o1 = ((unsigned)e1 << 6) + (fq << 2);
        const float4 q0 = *(const float4*)(Qb + o0);
        float4       v0 = *(const float4*)(Vb + o0);
        const float4 q1 = *(const float4*)(Qb + o1);
        float4       v1 = *(const float4*)(Vb + o1);
        if (rem < 8){                     // tail: mask inactive slots
            const float m0 = (2*sub   < rem) ? 1.f : 0.f;
            const float m1 = (2*sub+1 < rem) ? 1.f : 0.f;
            v0.x*=m0; v0.y*=m0; v0.z*=m0; v0.w*=m0;
            v1.x*=m1; v1.y*=m1; v1.z*=m1; v1.w*=m1;
        }
        float g;
        g = kf.x+q0.x; g = fmaxf(g, 0.01f*g); acc.x = fmaf(g, v0.x, acc.x);
        g = kf.y+q0.y; g = fmaxf(g, 0.01f*g); acc.y = fmaf(g, v0.y, acc.y);
        g = kf.z+q0.z; g = fmaxf(g, 0.01f*g); acc.z = fmaf(g, v0.z, acc.z);
        g = kf.w+q0.w; g = fmaxf(g, 0.01f*g); acc.w = fmaf(g, v0.w, acc.w);
        g = kf.x+q1.x; g = fmaxf(g, 0.01f*g); acc.x = fmaf(g, v1.x, acc.x);
        g = kf.y+q1.y; g = fmaxf(g, 0.01f*g); acc.y = fmaf(g, v1.y, acc.y);
        g = kf.z+q1.z; g = fmaxf(g, 0.01f*g); acc.z = fmaf(g, v1.z, acc.z);
        g = kf.w+q1.w; g = fmaxf(g, 0.01f*g); acc.w = fmaf(g, v1.w, acc.w);
    }

    // merge the 4 edge groups (lanes fq, fq+16, fq+32, fq+48)
    acc.x += __shfl_xor(acc.x, 16, 64); acc.y += __shfl_xor(acc.y, 16, 64);
    acc.z += __shfl_xor(acc.z, 16, 64); acc.w += __shfl_xor(acc.w, 16, 64);
    acc.x += __shfl_xor(acc.x, 32, 64); acc.y += __shfl_xor(acc.y, 32, 64);
    acc.z += __shfl_xor(acc.z, 32, 64); acc.w += __shfl_xor(acc.w, 32, 64);

    if (sub == 0){
        const float4 sk = *(const float4*)(out + rowb + fq*4);  // skip+bias
        float4 r;
        r.x = acc.x + sk.x; r.y = acc.y + sk.y;
        r.z = acc.z + sk.z; r.w = acc.w + sk.w;
        *(float4*)(out + rowb + fq*4) = r;
    }
}

extern "C" void kernel_launch(void* const* d_in, const int* in_sizes, int n_in,
                              void* d_out, int out_size, void* d_ws, size_t ws_size,
                              hipStream_t stream)
{
    const float* x  = (const float*)d_in[0];
    const unsigned int* ew = (const unsigned int*)d_in[1];
    const float* Wk = (const float*)d_in[2];
    const float* bk = (const float*)d_in[3];
    const float* Wq = (const float*)d_in[4];
    const float* bq = (const float*)d_in[5];
    const float* Wv = (const float*)d_in[6];
    const float* bv = (const float*)d_in[7];
    const float* Ws = (const float*)d_in[8];
    const float* bs = (const float*)d_in[9];
    float* out = (float*)d_out;

    float* K = (float*)d_ws;
    const size_t n = (size_t)ROWS*FF;
    float* Q = K + n;
    float* V = Q + n;
    int* meta  = (int*)(V + n);
    int* flag  = meta;
    int* deg   = meta + 16;
    int* offs  = deg + NN;
    int* cur   = offs + NN + 16;
    int* elist = cur + NN;

    hipLaunchKernelGGL(proj_kernel, dim3(ROWS/PR_ROWS), dim3(128), 0, stream,
                       x, Wk,bk, Wq,bq, Wv,bv, Ws,bs, K,Q,V, out);
    hipLaunchKernelGGL(csr_init_kernel,  dim3(1),  dim3(256),  0, stream, ew, flag, deg, elist);
    hipLaunchKernelGGL(csr_hist_kernel,  dim3(64), dim3(256),  0, stream, ew, flag, deg);
    hipLaunchKernelGGL(csr_scan_kernel,  dim3(1),  dim3(1024), 0, stream, deg, offs, cur);
    hipLaunchKernelGGL(csr_place_kernel, dim3(64), dim3(256),  0, stream, ew, flag, cur, elist);
    hipLaunchKernelGGL(agg_kernel, dim3(ROWS/4), dim3(256), 0, stream,
                       K, Q, V, offs, elist, out);
}